// Round 1
// baseline (666.054 us; speedup 1.0000x reference)
//
#include <hip/hip_runtime.h>

// ---------------------------------------------------------------------------
// GCN model: 3x GCNConv (self-loop sym-norm) + out-linear + mean-pool,
// MLP branch, concat, 2-layer pred head, scalar out. All fp32.
// ---------------------------------------------------------------------------

__global__ void k_zero(int* deg, float* pool, float* cnt, int N, int G) {
    int i = blockIdx.x * blockDim.x + threadIdx.x;
    if (i < N) deg[i] = 0;
    if (i < G * 128) pool[i] = 0.f;
    if (i < G) cnt[i] = 0.f;
}

__global__ void k_degree(const int* __restrict__ col, int* __restrict__ deg, int E) {
    int e = blockIdx.x * blockDim.x + threadIdx.x;
    if (e < E) atomicAdd(&deg[col[e]], 1);
}

// Single-block hierarchical exclusive scan of deg[0..n) -> rowptr, cursor.
__global__ __launch_bounds__(1024) void k_scan(const int* __restrict__ deg,
                                               int* __restrict__ rowptr,
                                               int* __restrict__ cursor, int n) {
    __shared__ int wsum[16];
    __shared__ int s_carry;
    const int tid = threadIdx.x;
    const int lane = tid & 63, wv = tid >> 6;
    if (tid == 0) s_carry = 0;
    __syncthreads();
    for (int base = 0; base < n; base += 1024) {
        int i = base + tid;
        int v = (i < n) ? deg[i] : 0;
        int x = v;
        #pragma unroll
        for (int off = 1; off < 64; off <<= 1) {
            int t = __shfl_up(x, off, 64);
            if (lane >= off) x += t;
        }
        if (lane == 63) wsum[wv] = x;
        __syncthreads();
        int woff = 0;
        for (int w = 0; w < wv; ++w) woff += wsum[w];
        int excl = s_carry + woff + (x - v);
        if (i < n) { rowptr[i] = excl; cursor[i] = excl; }
        __syncthreads();
        if (tid == 1023) s_carry = excl + v;   // grand inclusive total
        __syncthreads();
    }
    if (tid == 0) rowptr[n] = s_carry;
}

__global__ void k_dinv(const int* __restrict__ deg, float* __restrict__ dinv, int N) {
    int i = blockIdx.x * blockDim.x + threadIdx.x;
    if (i < N) dinv[i] = rsqrtf((float)deg[i] + 1.0f);
}

__global__ void k_scatter(const int* __restrict__ row, const int* __restrict__ col,
                          int* __restrict__ cursor, int* __restrict__ csr_src, int E) {
    int e = blockIdx.x * blockDim.x + threadIdx.x;
    if (e < E) {
        int pos = atomicAdd(&cursor[col[e]], 1);
        csr_src[pos] = row[e];
    }
}

// WT[l][k][o] = W_l[o][k] for l in {0,1,2 (gcn_W), 3 (gcn_out_W)}
__global__ void k_transpose_w(const float* __restrict__ gcnW,
                              const float* __restrict__ gcnoW,
                              float* __restrict__ WT) {
    int idx = blockIdx.x * 256 + threadIdx.x;   // 65536 threads
    int l = idx >> 14, rem = idx & 16383;
    int k = rem >> 7, o = rem & 127;
    const float* src = (l < 3) ? (gcnW + l * 16384) : gcnoW;
    WT[idx] = src[o * 128 + k];
}

// C[N,128] = A[N,128] @ W^T, with WT (=[k][o]) input. 64-row tile, 4x8/thread.
// As is XOR-swizzled (key = (row>>2)&3) so the 4 per-k A reads hit 4 banks.
__global__ __launch_bounds__(256, 2) void k_matmul(const float* __restrict__ A,
                                                   const float* __restrict__ WT,
                                                   float* __restrict__ C, int N) {
    __shared__ float As[64 * 128];   // 32 KB
    __shared__ float Ws[64 * 128];   // 32 KB
    const int tid = threadIdx.x;
    const int row0 = blockIdx.x * 64;
    const int tr = tid >> 4;     // 0..15 -> rows 4*tr..+3
    const int tc = tid & 15;     // 0..15 -> cols 8*tc..+7
    const int c_swz = (tr & 3) << 3;

    // stage A tile (64 rows x 128 cols), swizzled store, coalesced load
    #pragma unroll
    for (int i = 0; i < 8; ++i) {
        int v = tid + i * 256;             // 0..2047 float4 slots
        int r = v >> 5, k4 = v & 31;
        int gr = row0 + r;
        float4 val = make_float4(0.f, 0.f, 0.f, 0.f);
        if (gr < N) val = *(const float4*)(A + (size_t)gr * 128 + k4 * 4);
        int sc = (k4 * 4) ^ (((r >> 2) & 3) << 3);
        *(float4*)(&As[r * 128 + sc]) = val;
    }

    float acc[4][8];
    #pragma unroll
    for (int j = 0; j < 4; ++j)
        #pragma unroll
        for (int c = 0; c < 8; ++c) acc[j][c] = 0.f;

    for (int kt = 0; kt < 2; ++kt) {
        __syncthreads();
        // stage W k-rows kt*64..+63 (row-major [kk][o]) — coalesced, no conflicts
        #pragma unroll
        for (int i = 0; i < 8; ++i) {
            int v = tid + i * 256;
            int kk = v >> 5, o4 = v & 31;
            *(float4*)(&Ws[kk * 128 + o4 * 4]) =
                *(const float4*)(WT + (size_t)(kt * 64 + kk) * 128 + o4 * 4);
        }
        __syncthreads();
        #pragma unroll 8
        for (int kk = 0; kk < 64; ++kk) {
            int k = kt * 64 + kk;
            float a[4];
            #pragma unroll
            for (int j = 0; j < 4; ++j)
                a[j] = As[(4 * tr + j) * 128 + (k ^ c_swz)];
            float4 w0 = *(const float4*)(&Ws[kk * 128 + tc * 8]);
            float4 w1 = *(const float4*)(&Ws[kk * 128 + tc * 8 + 4]);
            #pragma unroll
            for (int j = 0; j < 4; ++j) {
                acc[j][0] += a[j] * w0.x; acc[j][1] += a[j] * w0.y;
                acc[j][2] += a[j] * w0.z; acc[j][3] += a[j] * w0.w;
                acc[j][4] += a[j] * w1.x; acc[j][5] += a[j] * w1.y;
                acc[j][6] += a[j] * w1.z; acc[j][7] += a[j] * w1.w;
            }
        }
    }

    #pragma unroll
    for (int j = 0; j < 4; ++j) {
        int gr = row0 + 4 * tr + j;
        if (gr < N) {
            *(float4*)(C + (size_t)gr * 128 + tc * 8) =
                make_float4(acc[j][0], acc[j][1], acc[j][2], acc[j][3]);
            *(float4*)(C + (size_t)gr * 128 + tc * 8 + 4) =
                make_float4(acc[j][4], acc[j][5], acc[j][6], acc[j][7]);
        }
    }
}

// One block (128 threads) per node: dst[n] = relu(dinv[n]*sum_e dinv[src]*h[src]
//                                               + dinv[n]^2*h[n] + bias)
__global__ __launch_bounds__(128) void k_agg(const float* __restrict__ h,
                                             float* __restrict__ dst,
                                             const float* __restrict__ dinv,
                                             const float* __restrict__ bias,
                                             const int* __restrict__ rowptr,
                                             const int* __restrict__ csr_src, int N) {
    int n = blockIdx.x;
    int t = threadIdx.x;
    __shared__ int s_src[64];
    __shared__ float s_w[64];
    int s = rowptr[n], e = rowptr[n + 1];
    float acc = 0.f;
    for (int base = s; base < e; base += 64) {
        int m = min(64, e - base);
        if (t < m) {
            int src = csr_src[base + t];
            s_src[t] = src;
            s_w[t] = dinv[src];
        }
        __syncthreads();
        for (int j = 0; j < m; ++j)
            acc += s_w[j] * h[(size_t)s_src[j] * 128 + t];
        __syncthreads();
    }
    float dn = dinv[n];
    float val = acc * dn + dn * dn * h[(size_t)n * 128 + t] + bias[t];
    dst[(size_t)n * 128 + t] = fmaxf(val, 0.f);
}

// Run-length segmented mean-pool accumulate (batch_index is sorted).
__global__ __launch_bounds__(128) void k_pool(const float* __restrict__ hout,
                                              const int* __restrict__ batch,
                                              float* __restrict__ pool,
                                              float* __restrict__ cnt, int N) {
    int t = threadIdx.x;
    int n0 = blockIdx.x * 128;
    if (n0 >= N) return;
    int n1 = min(n0 + 128, N);
    int gprev = batch[n0];
    float racc = 0.f, rcnt = 0.f;
    for (int n = n0; n < n1; ++n) {
        int g = batch[n];
        if (g != gprev) {
            atomicAdd(&pool[(size_t)gprev * 128 + t], racc);
            if (t == 0) atomicAdd(&cnt[gprev], rcnt);
            racc = 0.f; rcnt = 0.f; gprev = g;
        }
        racc += hout[(size_t)n * 128 + t];
        rcnt += 1.f;
    }
    atomicAdd(&pool[(size_t)gprev * 128 + t], racc);
    if (t == 0) atomicAdd(&cnt[gprev], rcnt);
}

// Fused head: per-graph row stays in LDS through MLP branch, concat, pred head.
__global__ __launch_bounds__(256) void k_head(
    const float* __restrict__ pool, const float* __restrict__ cnt,
    const float* __restrict__ gcnob, const float* __restrict__ mol,
    const float* __restrict__ mlpW, const float* __restrict__ mlpb,
    const float* __restrict__ mloW, const float* __restrict__ mlob,
    const float* __restrict__ pW1, const float* __restrict__ pb1,
    const float* __restrict__ pW2, const float* __restrict__ pb2,
    const float* __restrict__ oW, const float* __restrict__ ob,
    float* __restrict__ out) {
    int g = blockIdx.x, t = threadIdx.x;
    __shared__ float s0[256], s1[256], s2[192], red[256];

    s0[t] = mol[(size_t)g * 256 + t];
    __syncthreads();

    // mlp layer 0: s1 = relu(s0 @ W0^T + b0)
    float acc = mlpb[t];
    {
        const float4* w = (const float4*)(mlpW + (size_t)t * 256);
        #pragma unroll 4
        for (int k4 = 0; k4 < 64; ++k4) {
            float4 wv = w[k4];
            acc += s0[k4*4+0]*wv.x + s0[k4*4+1]*wv.y + s0[k4*4+2]*wv.z + s0[k4*4+3]*wv.w;
        }
    }
    s1[t] = fmaxf(acc, 0.f);
    __syncthreads();

    // mlp layer 1: s0 = relu(s1 @ W1^T + b1)
    acc = mlpb[256 + t];
    {
        const float4* w = (const float4*)(mlpW + 65536 + (size_t)t * 256);
        #pragma unroll 4
        for (int k4 = 0; k4 < 64; ++k4) {
            float4 wv = w[k4];
            acc += s1[k4*4+0]*wv.x + s1[k4*4+1]*wv.y + s1[k4*4+2]*wv.z + s1[k4*4+3]*wv.w;
        }
    }
    s0[t] = fmaxf(acc, 0.f);
    __syncthreads();

    // mlp_out (64 outs, relu) -> s2[128..191]
    if (t < 64) {
        float a2 = mlob[t];
        const float4* w = (const float4*)(mloW + (size_t)t * 256);
        #pragma unroll 4
        for (int k4 = 0; k4 < 64; ++k4) {
            float4 wv = w[k4];
            a2 += s0[k4*4+0]*wv.x + s0[k4*4+1]*wv.y + s0[k4*4+2]*wv.z + s0[k4*4+3]*wv.w;
        }
        s2[128 + t] = fmaxf(a2, 0.f);
    }
    // gcn branch: mean-pool + out-linear bias (no relu) -> s2[0..127]
    if (t < 128) {
        float c = cnt[g];
        s2[t] = pool[(size_t)g * 128 + t] / fmaxf(c, 1.f) + gcnob[t];
    }
    __syncthreads();

    // pred1: s1 = relu(s2(192) @ pW1^T + pb1)
    acc = pb1[t];
    {
        const float4* w = (const float4*)(pW1 + (size_t)t * 192);
        #pragma unroll 4
        for (int k4 = 0; k4 < 48; ++k4) {
            float4 wv = w[k4];
            acc += s2[k4*4+0]*wv.x + s2[k4*4+1]*wv.y + s2[k4*4+2]*wv.z + s2[k4*4+3]*wv.w;
        }
    }
    s1[t] = fmaxf(acc, 0.f);
    __syncthreads();

    // pred2: s0 = relu(s1 @ pW2^T + pb2)
    acc = pb2[t];
    {
        const float4* w = (const float4*)(pW2 + (size_t)t * 256);
        #pragma unroll 4
        for (int k4 = 0; k4 < 64; ++k4) {
            float4 wv = w[k4];
            acc += s1[k4*4+0]*wv.x + s1[k4*4+1]*wv.y + s1[k4*4+2]*wv.z + s1[k4*4+3]*wv.w;
        }
    }
    s0[t] = fmaxf(acc, 0.f);
    __syncthreads();

    // out: scalar reduction
    red[t] = s0[t] * oW[t];
    __syncthreads();
    for (int off = 128; off > 0; off >>= 1) {
        if (t < off) red[t] += red[t + off];
        __syncthreads();
    }
    if (t == 0) out[g] = red[0] + ob[0];
}

extern "C" void kernel_launch(void* const* d_in, const int* in_sizes, int n_in,
                              void* d_out, int out_size, void* d_ws, size_t ws_size,
                              hipStream_t stream) {
    const float* x     = (const float*)d_in[0];
    const int*   ei    = (const int*)d_in[1];
    const int*   batch = (const int*)d_in[2];
    const float* mol   = (const float*)d_in[3];
    const float* gcnW  = (const float*)d_in[4];
    const float* gcnb  = (const float*)d_in[5];
    const float* gcnoW = (const float*)d_in[6];
    const float* gcnob = (const float*)d_in[7];
    const float* mlpW  = (const float*)d_in[8];
    const float* mlpb  = (const float*)d_in[9];
    const float* mloW  = (const float*)d_in[10];
    const float* mlob  = (const float*)d_in[11];
    const float* pW1   = (const float*)d_in[12];
    const float* pb1   = (const float*)d_in[13];
    const float* pW2   = (const float*)d_in[14];
    const float* pb2   = (const float*)d_in[15];
    const float* oW    = (const float*)d_in[16];
    const float* ob    = (const float*)d_in[17];

    const int N = in_sizes[0] / 128;
    const int E = in_sizes[1] / 2;
    const int G = in_sizes[3] / 256;
    const int* row = ei;
    const int* col = ei + E;

    char* p = (char*)d_ws;
    auto alloc = [&](size_t bytes) {
        char* q = p;
        p += (bytes + 255) & ~(size_t)255;
        return (void*)q;
    };
    int*   deg     = (int*)alloc((size_t)N * 4);
    int*   rowptr  = (int*)alloc((size_t)(N + 1) * 4);
    int*   cursor  = (int*)alloc((size_t)N * 4);
    int*   csr_src = (int*)alloc((size_t)E * 4);
    float* dinv    = (float*)alloc((size_t)N * 4);
    float* buf0    = (float*)alloc((size_t)N * 128 * 4);
    float* buf1    = (float*)alloc((size_t)N * 128 * 4);
    float* WT      = (float*)alloc((size_t)4 * 128 * 128 * 4);
    float* pool    = (float*)alloc((size_t)G * 128 * 4);
    float* cnt     = (float*)alloc((size_t)G * 4);

    k_zero<<<(N + 255) / 256, 256, 0, stream>>>(deg, pool, cnt, N, G);
    k_degree<<<(E + 255) / 256, 256, 0, stream>>>(col, deg, E);
    k_scan<<<1, 1024, 0, stream>>>(deg, rowptr, cursor, N);
    k_dinv<<<(N + 255) / 256, 256, 0, stream>>>(deg, dinv, N);
    k_scatter<<<(E + 255) / 256, 256, 0, stream>>>(row, col, cursor, csr_src, E);
    k_transpose_w<<<256, 256, 0, stream>>>(gcnW, gcnoW, WT);

    const int mmblocks = (N + 63) / 64;
    const float* src = x;
    for (int l = 0; l < 3; ++l) {
        k_matmul<<<mmblocks, 256, 0, stream>>>(src, WT + (size_t)l * 16384, buf1, N);
        k_agg<<<N, 128, 0, stream>>>(buf1, buf0, dinv, gcnb + (size_t)l * 128,
                                     rowptr, csr_src, N);
        src = buf0;
    }
    k_matmul<<<mmblocks, 256, 0, stream>>>(buf0, WT + 3 * 16384, buf1, N);
    k_pool<<<(N + 127) / 128, 128, 0, stream>>>(buf1, batch, pool, cnt, N);
    k_head<<<G, 256, 0, stream>>>(pool, cnt, gcnob, mol, mlpW, mlpb, mloW, mlob,
                                  pW1, pb1, pW2, pb2, oW, ob, (float*)d_out);
}

// Round 2
// 552.308 us; speedup vs baseline: 1.2059x; 1.2059x over previous
//
#include <hip/hip_runtime.h>

// ---------------------------------------------------------------------------
// GCN model, re-associated: per layer h = relu((A_hat @ h_prev) @ W^T + b);
// pool BEFORE gcn_out linear (both linear, commute). All fp32.
// ---------------------------------------------------------------------------

__global__ void k_zero(int* deg, float* pool, float* cnt, int N, int G) {
    int i = blockIdx.x * blockDim.x + threadIdx.x;
    if (i < N) deg[i] = 0;
    if (i < G * 128) pool[i] = 0.f;
    if (i < G) cnt[i] = 0.f;
}

__global__ void k_degree(const int* __restrict__ col, int* __restrict__ deg, int E) {
    int e = blockIdx.x * blockDim.x + threadIdx.x;
    if (e < E) atomicAdd(&deg[col[e]], 1);
}

// ---- 3-phase multi-block exclusive scan of deg -> rowptr/cursor (+dinv) ----
__global__ __launch_bounds__(256) void k_scan1(const int* __restrict__ deg,
                                               int* __restrict__ bsum, int N) {
    int t = threadIdx.x;
    int i = blockIdx.x * 256 + t;
    int v = (i < N) ? deg[i] : 0;
    #pragma unroll
    for (int off = 32; off > 0; off >>= 1) v += __shfl_xor(v, off, 64);
    __shared__ int ws[4];
    if ((t & 63) == 0) ws[t >> 6] = v;
    __syncthreads();
    if (t == 0) bsum[blockIdx.x] = ws[0] + ws[1] + ws[2] + ws[3];
}

// NB <= 256 (N=50000 -> NB=196). Exclusive scan of bsum in place.
__global__ __launch_bounds__(256) void k_scan2(int* __restrict__ bsum, int NB) {
    int t = threadIdx.x, lane = t & 63, wv = t >> 6;
    int v = (t < NB) ? bsum[t] : 0;
    int x = v;
    #pragma unroll
    for (int off = 1; off < 64; off <<= 1) {
        int u = __shfl_up(x, off, 64);
        if (lane >= off) x += u;
    }
    __shared__ int ws[4];
    if (lane == 63) ws[wv] = x;
    __syncthreads();
    int woff = 0;
    for (int w = 0; w < wv; ++w) woff += ws[w];
    if (t < NB) bsum[t] = woff + x - v;
}

__global__ __launch_bounds__(256) void k_scan3(const int* __restrict__ deg,
                                               const int* __restrict__ bsum,
                                               int* __restrict__ rowptr,
                                               int* __restrict__ cursor,
                                               float* __restrict__ dinv,
                                               int N, int E) {
    int t = threadIdx.x, lane = t & 63, wv = t >> 6;
    int i = blockIdx.x * 256 + t;
    int v = (i < N) ? deg[i] : 0;
    int x = v;
    #pragma unroll
    for (int off = 1; off < 64; off <<= 1) {
        int u = __shfl_up(x, off, 64);
        if (lane >= off) x += u;
    }
    __shared__ int ws[4];
    if (lane == 63) ws[wv] = x;
    __syncthreads();
    int woff = 0;
    for (int w = 0; w < wv; ++w) woff += ws[w];
    int excl = bsum[blockIdx.x] + woff + (x - v);
    if (i < N) {
        rowptr[i] = excl;
        cursor[i] = excl;
        dinv[i] = rsqrtf((float)v + 1.0f);
    }
    if (i == 0) rowptr[N] = E;
}

__global__ void k_scatter(const int* __restrict__ row, const int* __restrict__ col,
                          int* __restrict__ cursor, int* __restrict__ csr_src, int E) {
    int e = blockIdx.x * blockDim.x + threadIdx.x;
    if (e < E) {
        int pos = atomicAdd(&cursor[col[e]], 1);
        csr_src[pos] = row[e];
    }
}

// WT[l][k][o] = gcn_W[l][o][k], l in {0,1,2}
__global__ void k_transpose_w(const float* __restrict__ gcnW, float* __restrict__ WT) {
    int idx = blockIdx.x * 256 + threadIdx.x;   // 49152 threads
    int l = idx >> 14, rem = idx & 16383;
    int k = rem >> 7, o = rem & 127;
    WT[idx] = gcnW[l * 16384 + o * 128 + k];
}

// y[n] = dinv[n] * sum_{src in nbrs(n)} dinv[src]*h[src] + dinv[n]^2 * h[n]
// 128 threads: 4 neighbor slots x 32 feature-groups (float4 each).
__global__ __launch_bounds__(128) void k_agg(const float* __restrict__ h,
                                             float* __restrict__ y,
                                             const float* __restrict__ dinv,
                                             const int* __restrict__ rowptr,
                                             const int* __restrict__ csr_src, int N) {
    const int n = blockIdx.x;
    const int t = threadIdx.x;
    const int fg = t & 31, slot = t >> 5;
    __shared__ int   s_src[64];
    __shared__ float s_w[64];
    __shared__ float s_red[3][32][4];
    const int s = rowptr[n], e = rowptr[n + 1];
    float4 acc = make_float4(0.f, 0.f, 0.f, 0.f);
    for (int base = s; base < e; base += 64) {
        int m = min(64, e - base);
        if (t < m) {
            int src = csr_src[base + t];
            s_src[t] = src;
            s_w[t] = dinv[src];
        }
        __syncthreads();
        #pragma unroll 4
        for (int jb = 0; jb < m; jb += 4) {
            int j = jb + slot;
            if (j < m) {
                float w = s_w[j];
                float4 v = *(const float4*)(h + (size_t)s_src[j] * 128 + fg * 4);
                acc.x += w * v.x; acc.y += w * v.y;
                acc.z += w * v.z; acc.w += w * v.w;
            }
        }
        __syncthreads();
    }
    if (slot > 0) *(float4*)&s_red[slot - 1][fg][0] = acc;
    __syncthreads();
    if (slot == 0) {
        #pragma unroll
        for (int k = 0; k < 3; ++k) {
            float4 o = *(float4*)&s_red[k][fg][0];
            acc.x += o.x; acc.y += o.y; acc.z += o.z; acc.w += o.w;
        }
        float dn = dinv[n], dn2 = dn * dn;
        float4 hv = *(const float4*)(h + (size_t)n * 128 + fg * 4);
        float4 out;
        out.x = acc.x * dn + dn2 * hv.x;
        out.y = acc.y * dn + dn2 * hv.y;
        out.z = acc.z * dn + dn2 * hv.z;
        out.w = acc.w * dn + dn2 * hv.w;
        *(float4*)(y + (size_t)n * 128 + fg * 4) = out;
    }
}

// C[N,128] = relu(A[N,128] @ W^T + bias). WT is [k][o]. 64-row tile, 4x8/thread.
__global__ __launch_bounds__(256, 2) void k_matmul(const float* __restrict__ A,
                                                   const float* __restrict__ WT,
                                                   const float* __restrict__ bias,
                                                   float* __restrict__ C, int N) {
    __shared__ float As[64 * 128];   // 32 KB
    __shared__ float Ws[64 * 128];   // 32 KB
    const int tid = threadIdx.x;
    const int row0 = blockIdx.x * 64;
    const int tr = tid >> 4;     // 0..15 -> rows 4*tr..+3
    const int tc = tid & 15;     // 0..15 -> cols 8*tc..+7
    const int c_swz = (tr & 3) << 3;

    #pragma unroll
    for (int i = 0; i < 8; ++i) {
        int v = tid + i * 256;
        int r = v >> 5, k4 = v & 31;
        int gr = row0 + r;
        float4 val = make_float4(0.f, 0.f, 0.f, 0.f);
        if (gr < N) val = *(const float4*)(A + (size_t)gr * 128 + k4 * 4);
        int sc = (k4 * 4) ^ (((r >> 2) & 3) << 3);
        *(float4*)(&As[r * 128 + sc]) = val;
    }

    float acc[4][8];
    #pragma unroll
    for (int j = 0; j < 4; ++j)
        #pragma unroll
        for (int c = 0; c < 8; ++c) acc[j][c] = 0.f;

    for (int kt = 0; kt < 2; ++kt) {
        __syncthreads();
        #pragma unroll
        for (int i = 0; i < 8; ++i) {
            int v = tid + i * 256;
            int kk = v >> 5, o4 = v & 31;
            *(float4*)(&Ws[kk * 128 + o4 * 4]) =
                *(const float4*)(WT + (size_t)(kt * 64 + kk) * 128 + o4 * 4);
        }
        __syncthreads();
        #pragma unroll 8
        for (int kk = 0; kk < 64; ++kk) {
            int k = kt * 64 + kk;
            float a[4];
            #pragma unroll
            for (int j = 0; j < 4; ++j)
                a[j] = As[(4 * tr + j) * 128 + (k ^ c_swz)];
            float4 w0 = *(const float4*)(&Ws[kk * 128 + tc * 8]);
            float4 w1 = *(const float4*)(&Ws[kk * 128 + tc * 8 + 4]);
            #pragma unroll
            for (int j = 0; j < 4; ++j) {
                acc[j][0] += a[j] * w0.x; acc[j][1] += a[j] * w0.y;
                acc[j][2] += a[j] * w0.z; acc[j][3] += a[j] * w0.w;
                acc[j][4] += a[j] * w1.x; acc[j][5] += a[j] * w1.y;
                acc[j][6] += a[j] * w1.z; acc[j][7] += a[j] * w1.w;
            }
        }
    }

    float4 b0 = *(const float4*)(bias + tc * 8);
    float4 b1 = *(const float4*)(bias + tc * 8 + 4);
    #pragma unroll
    for (int j = 0; j < 4; ++j) {
        int gr = row0 + 4 * tr + j;
        if (gr < N) {
            float4 o0 = make_float4(fmaxf(acc[j][0] + b0.x, 0.f),
                                    fmaxf(acc[j][1] + b0.y, 0.f),
                                    fmaxf(acc[j][2] + b0.z, 0.f),
                                    fmaxf(acc[j][3] + b0.w, 0.f));
            float4 o1 = make_float4(fmaxf(acc[j][4] + b1.x, 0.f),
                                    fmaxf(acc[j][5] + b1.y, 0.f),
                                    fmaxf(acc[j][6] + b1.z, 0.f),
                                    fmaxf(acc[j][7] + b1.w, 0.f));
            *(float4*)(C + (size_t)gr * 128 + tc * 8) = o0;
            *(float4*)(C + (size_t)gr * 128 + tc * 8 + 4) = o1;
        }
    }
}

// Mean-pool accumulate (batch sorted). 256 threads = 8 subgroups of 32 lanes;
// subgroup sg handles nodes [n0+32*sg, n0+32*sg+32), float4 per lane.
__global__ __launch_bounds__(256) void k_pool(const float* __restrict__ h,
                                              const int* __restrict__ batch,
                                              float* __restrict__ pool,
                                              float* __restrict__ cnt, int N) {
    int t = threadIdx.x;
    int fg = t & 31, sg = t >> 5;
    int n0 = blockIdx.x * 256 + sg * 32;
    if (n0 >= N) return;
    int n1 = min(n0 + 32, N);
    int gprev = batch[n0];
    float4 racc = make_float4(0.f, 0.f, 0.f, 0.f);
    float rcnt = 0.f;
    for (int n = n0; n < n1; ++n) {
        int g = batch[n];
        if (g != gprev) {
            float* dst = pool + (size_t)gprev * 128 + fg * 4;
            atomicAdd(dst + 0, racc.x); atomicAdd(dst + 1, racc.y);
            atomicAdd(dst + 2, racc.z); atomicAdd(dst + 3, racc.w);
            if (fg == 0) atomicAdd(&cnt[gprev], rcnt);
            racc = make_float4(0.f, 0.f, 0.f, 0.f); rcnt = 0.f; gprev = g;
        }
        float4 v = *(const float4*)(h + (size_t)n * 128 + fg * 4);
        racc.x += v.x; racc.y += v.y; racc.z += v.z; racc.w += v.w;
        rcnt += 1.f;
    }
    float* dst = pool + (size_t)gprev * 128 + fg * 4;
    atomicAdd(dst + 0, racc.x); atomicAdd(dst + 1, racc.y);
    atomicAdd(dst + 2, racc.z); atomicAdd(dst + 3, racc.w);
    if (fg == 0) atomicAdd(&cnt[gprev], rcnt);
}

// Fused head. gcn branch: mean -> gcn_out linear (moved after pooling).
__global__ __launch_bounds__(256) void k_head(
    const float* __restrict__ pool, const float* __restrict__ cnt,
    const float* __restrict__ gcnoW, const float* __restrict__ gcnob,
    const float* __restrict__ mol,
    const float* __restrict__ mlpW, const float* __restrict__ mlpb,
    const float* __restrict__ mloW, const float* __restrict__ mlob,
    const float* __restrict__ pW1, const float* __restrict__ pb1,
    const float* __restrict__ pW2, const float* __restrict__ pb2,
    const float* __restrict__ oW, const float* __restrict__ ob,
    float* __restrict__ out) {
    int g = blockIdx.x, t = threadIdx.x;
    __shared__ float s0[256], s1[256], s2[192], mean[128], red[256];

    s0[t] = mol[(size_t)g * 256 + t];
    if (t < 128) {
        float c = cnt[g];
        mean[t] = pool[(size_t)g * 128 + t] / fmaxf(c, 1.f);
    }
    __syncthreads();

    // mlp layer 0
    float acc = mlpb[t];
    {
        const float4* w = (const float4*)(mlpW + (size_t)t * 256);
        #pragma unroll 4
        for (int k4 = 0; k4 < 64; ++k4) {
            float4 wv = w[k4];
            acc += s0[k4*4+0]*wv.x + s0[k4*4+1]*wv.y + s0[k4*4+2]*wv.z + s0[k4*4+3]*wv.w;
        }
    }
    s1[t] = fmaxf(acc, 0.f);
    __syncthreads();

    // mlp layer 1
    acc = mlpb[256 + t];
    {
        const float4* w = (const float4*)(mlpW + 65536 + (size_t)t * 256);
        #pragma unroll 4
        for (int k4 = 0; k4 < 64; ++k4) {
            float4 wv = w[k4];
            acc += s1[k4*4+0]*wv.x + s1[k4*4+1]*wv.y + s1[k4*4+2]*wv.z + s1[k4*4+3]*wv.w;
        }
    }
    s0[t] = fmaxf(acc, 0.f);
    __syncthreads();

    // mlp_out (64 outs, relu) -> s2[128..191]; gcn out-linear -> s2[0..127]
    if (t < 64) {
        float a2 = mlob[t];
        const float4* w = (const float4*)(mloW + (size_t)t * 256);
        #pragma unroll 4
        for (int k4 = 0; k4 < 64; ++k4) {
            float4 wv = w[k4];
            a2 += s0[k4*4+0]*wv.x + s0[k4*4+1]*wv.y + s0[k4*4+2]*wv.z + s0[k4*4+3]*wv.w;
        }
        s2[128 + t] = fmaxf(a2, 0.f);
    } else if (t < 192) {
        int o = t - 64;
        float a2 = gcnob[o];
        const float4* w = (const float4*)(gcnoW + (size_t)o * 128);
        #pragma unroll 4
        for (int k4 = 0; k4 < 32; ++k4) {
            float4 wv = w[k4];
            a2 += mean[k4*4+0]*wv.x + mean[k4*4+1]*wv.y + mean[k4*4+2]*wv.z + mean[k4*4+3]*wv.w;
        }
        s2[o] = a2;   // no relu on gcn_out
    }
    __syncthreads();

    // pred1
    acc = pb1[t];
    {
        const float4* w = (const float4*)(pW1 + (size_t)t * 192);
        #pragma unroll 4
        for (int k4 = 0; k4 < 48; ++k4) {
            float4 wv = w[k4];
            acc += s2[k4*4+0]*wv.x + s2[k4*4+1]*wv.y + s2[k4*4+2]*wv.z + s2[k4*4+3]*wv.w;
        }
    }
    s1[t] = fmaxf(acc, 0.f);
    __syncthreads();

    // pred2
    acc = pb2[t];
    {
        const float4* w = (const float4*)(pW2 + (size_t)t * 256);
        #pragma unroll 4
        for (int k4 = 0; k4 < 64; ++k4) {
            float4 wv = w[k4];
            acc += s1[k4*4+0]*wv.x + s1[k4*4+1]*wv.y + s1[k4*4+2]*wv.z + s1[k4*4+3]*wv.w;
        }
    }
    s0[t] = fmaxf(acc, 0.f);
    __syncthreads();

    red[t] = s0[t] * oW[t];
    __syncthreads();
    for (int off = 128; off > 0; off >>= 1) {
        if (t < off) red[t] += red[t + off];
        __syncthreads();
    }
    if (t == 0) out[g] = red[0] + ob[0];
}

extern "C" void kernel_launch(void* const* d_in, const int* in_sizes, int n_in,
                              void* d_out, int out_size, void* d_ws, size_t ws_size,
                              hipStream_t stream) {
    const float* x     = (const float*)d_in[0];
    const int*   ei    = (const int*)d_in[1];
    const int*   batch = (const int*)d_in[2];
    const float* mol   = (const float*)d_in[3];
    const float* gcnW  = (const float*)d_in[4];
    const float* gcnb  = (const float*)d_in[5];
    const float* gcnoW = (const float*)d_in[6];
    const float* gcnob = (const float*)d_in[7];
    const float* mlpW  = (const float*)d_in[8];
    const float* mlpb  = (const float*)d_in[9];
    const float* mloW  = (const float*)d_in[10];
    const float* mlob  = (const float*)d_in[11];
    const float* pW1   = (const float*)d_in[12];
    const float* pb1   = (const float*)d_in[13];
    const float* pW2   = (const float*)d_in[14];
    const float* pb2   = (const float*)d_in[15];
    const float* oW    = (const float*)d_in[16];
    const float* ob    = (const float*)d_in[17];

    const int N = in_sizes[0] / 128;
    const int E = in_sizes[1] / 2;
    const int G = in_sizes[3] / 256;
    const int* row = ei;
    const int* col = ei + E;

    char* p = (char*)d_ws;
    auto alloc = [&](size_t bytes) {
        char* q = p;
        p += (bytes + 255) & ~(size_t)255;
        return (void*)q;
    };
    int*   deg     = (int*)alloc((size_t)N * 4);
    int*   rowptr  = (int*)alloc((size_t)(N + 1) * 4);
    int*   cursor  = (int*)alloc((size_t)N * 4);
    int*   csr_src = (int*)alloc((size_t)E * 4);
    float* dinv    = (float*)alloc((size_t)N * 4);
    float* buf0    = (float*)alloc((size_t)N * 128 * 4);
    float* buf1    = (float*)alloc((size_t)N * 128 * 4);
    float* WT      = (float*)alloc((size_t)3 * 128 * 128 * 4);
    float* pool    = (float*)alloc((size_t)G * 128 * 4);
    float* cnt     = (float*)alloc((size_t)G * 4);
    int*   bsum    = (int*)alloc(256 * 4);

    const int NB = (N + 255) / 256;   // 196 <= 256, required by k_scan2

    k_zero<<<(N + 255) / 256, 256, 0, stream>>>(deg, pool, cnt, N, G);
    k_degree<<<(E + 255) / 256, 256, 0, stream>>>(col, deg, E);
    k_scan1<<<NB, 256, 0, stream>>>(deg, bsum, N);
    k_scan2<<<1, 256, 0, stream>>>(bsum, NB);
    k_scan3<<<NB, 256, 0, stream>>>(deg, bsum, rowptr, cursor, dinv, N, E);
    k_scatter<<<(E + 255) / 256, 256, 0, stream>>>(row, col, cursor, csr_src, E);
    k_transpose_w<<<192, 256, 0, stream>>>(gcnW, WT);

    const int mmblocks = (N + 63) / 64;
    const float* src = x;
    for (int l = 0; l < 3; ++l) {
        k_agg<<<N, 128, 0, stream>>>(src, buf0, dinv, rowptr, csr_src, N);
        k_matmul<<<mmblocks, 256, 0, stream>>>(buf0, WT + (size_t)l * 16384,
                                               gcnb + (size_t)l * 128, buf1, N);
        src = buf1;
    }
    k_pool<<<NB, 256, 0, stream>>>(buf1, batch, pool, cnt, N);
    k_head<<<G, 256, 0, stream>>>(pool, cnt, gcnoW, gcnob, mol, mlpW, mlpb,
                                  mloW, mlob, pW1, pb1, pW2, pb2, oW, ob,
                                  (float*)d_out);
}